// Round 15
// baseline (214.258 us; speedup 1.0000x reference)
//
#include <hip/hip_runtime.h>

#define VOCAB 32000
#define EMB 32
#define HID 16
#define SEQ 128
#define BATCH 32
#define NROW (SEQ * BATCH)  // 4096 rows

typedef float f32x2 __attribute__((ext_vector_type(2)));
typedef float f32x4 __attribute__((ext_vector_type(4)));

// ---------------------------------------------------------------------------
// K0: A[t][b][j] = sum_e lookup[idx[t,b]][e] * Wx[e][j]  (parallel, R14).
// ---------------------------------------------------------------------------
__global__ __launch_bounds__(512) void embed_xw(
    const int* __restrict__ idx, const float* __restrict__ lookup,
    const float* __restrict__ Wx, float* __restrict__ A)
{
    __shared__ float sWx[EMB][HID];
    const int tid = threadIdx.x;
    ((float*)sWx)[tid] = Wx[tid];  // 512 == EMB*HID
    __syncthreads();

    const int g = blockIdx.x * 512 + tid;  // 0..65535
    const int row = g >> 4, j = g & 15;
    const float* xr = lookup + (size_t)idx[row] * EMB;
    float a0 = 0.f, a1 = 0.f;
    #pragma unroll
    for (int e = 0; e < EMB; e += 2) {
        a0 += xr[e] * sWx[e][j];
        a1 += xr[e + 1] * sWx[e + 1][j];
    }
    A[g] = a0 + a1;
}

// ---------------------------------------------------------------------------
// K1: serial recurrence, A precomputed (R14). One block, 512 thr = 32b x 16j.
// Per-step deps stay in a 16-lane group -> no per-step barrier (rounds 1-14).
// ---------------------------------------------------------------------------
__global__ __launch_bounds__(512) void rnn_recur(
    const float* __restrict__ A, const float* __restrict__ Wh,
    float* __restrict__ Hout)
{
    __shared__ __align__(16) float sH[BATCH][HID];

    const int tid = threadIdx.x;
    const int b = tid >> 4, j = tid & 15;

    float wh[HID];
    #pragma unroll
    for (int k = 0; k < HID; ++k) wh[k] = Wh[k * HID + j];  // column j

    sH[b][j] = 1.0f;  // torch inits H to ones
    __syncthreads();

    float a0r = A[0 * 512 + tid];
    float a1r = A[1 * 512 + tid];
    float a2r = A[2 * 512 + tid];
    float a3r = A[3 * 512 + tid];

#define RNN_STEP(AR, T)                                                     \
    {                                                                       \
        float acc = AR;                                                     \
        if ((T) + 4 < SEQ) AR = A[((T) + 4) * 512 + tid];                   \
        const f32x4* sH4 = (const f32x4*)&sH[b][0];                         \
        f32x4 h0 = sH4[0], h1 = sH4[1], h2v = sH4[2], h3v = sH4[3];         \
        acc += h0.x * wh[0] + h0.y * wh[1] + h0.z * wh[2] + h0.w * wh[3];   \
        acc += h1.x * wh[4] + h1.y * wh[5] + h1.z * wh[6] + h1.w * wh[7];   \
        acc += h2v.x * wh[8] + h2v.y * wh[9] + h2v.z * wh[10]               \
             + h2v.w * wh[11];                                              \
        acc += h3v.x * wh[12] + h3v.y * wh[13] + h3v.z * wh[14]             \
             + h3v.w * wh[15];                                              \
        float e2 = __expf(2.f * acc);   /* tanh = 1 - 2/(e^{2a}+1) */       \
        float h = 1.f - 2.f / (e2 + 1.f);                                   \
        sH[b][j] = h;                                                       \
        Hout[(T) * 512 + tid] = h;                                          \
    }

    for (int t = 0; t < SEQ; t += 4) {
        RNN_STEP(a0r, t + 0)
        RNN_STEP(a1r, t + 1)
        RNN_STEP(a2r, t + 2)
        RNN_STEP(a3r, t + 3)
    }
#undef RNN_STEP
}

// ---------------------------------------------------------------------------
// K2: sum-of-exp, LANE = ROW layout (R14, measured ~25us). Wave = 64 rows x
// 500-col slice; H per-lane in VGPRs; Wo wave-uniform (scalar path); in-lane
// accumulation (no cross-lane reduce, no LDS staging, no tail).
// ---------------------------------------------------------------------------
#define CSL 500  // cols per wave slice

__global__ __launch_bounds__(512, 4) void sum_exp_partial(
    const float* __restrict__ H, const float* __restrict__ Wo,
    float* __restrict__ P)
{
    __shared__ float part[8][64];

    const int tid = threadIdx.x;
    const int lane = tid & 63;
    const int wave = tid >> 6;                    // 0..7
    const int rgrp = blockIdx.x >> 3;             // 0..63
    const int cchunk = blockIdx.x & 7;            // 0..7
    const int row0 = rgrp * 64;
    const int c0 = __builtin_amdgcn_readfirstlane(cchunk * 4000 + wave * CSL);

    f32x2 hp[HID];
    {
        const f32x4* h4 = (const f32x4*)(H + (size_t)(row0 + lane) * HID);
        #pragma unroll
        for (int q = 0; q < 4; ++q) {
            f32x4 hv = h4[q];
            hp[4 * q + 0] = f32x2{hv.x, hv.x};
            hp[4 * q + 1] = f32x2{hv.y, hv.y};
            hp[4 * q + 2] = f32x2{hv.z, hv.z};
            hp[4 * q + 3] = f32x2{hv.w, hv.w};
        }
    }

    const float* wbase = Wo + c0;
    float acc0 = 0.f, acc1 = 0.f, acc2 = 0.f, acc3 = 0.f;
    for (int v = 0; v < CSL; v += 4) {
        f32x2 a01 = {0.f, 0.f}, a23 = {0.f, 0.f};
        #pragma unroll
        for (int k = 0; k < HID; ++k) {
            f32x4 w4 = *(const f32x4*)(wbase + (size_t)k * VOCAB + v);
            asm("v_pk_fma_f32 %0, %1, %2, %0"
                : "+v"(a01) : "v"(hp[k]), "s"(w4.xy));
            asm("v_pk_fma_f32 %0, %1, %2, %0"
                : "+v"(a23) : "v"(hp[k]), "s"(w4.zw));
        }
        acc0 += __expf(a01.x); acc1 += __expf(a01.y);
        acc2 += __expf(a23.x); acc3 += __expf(a23.y);
    }

    part[wave][lane] = (acc0 + acc1) + (acc2 + acc3);
    __syncthreads();
    if (wave == 0) {
        float tot = 0.f;
        #pragma unroll
        for (int w = 0; w < 8; ++w) tot += part[w][lane];
        P[(size_t)cchunk * NROW + row0 + lane] = tot;
    }
}

// ---------------------------------------------------------------------------
// K3 (v3): output pass with 8-ROW REGISTER BLOCKING + PLAIN aligned stores.
// R14 re-analysis: R11's "107us NT floor" may be L2-read-bound (per-row Wo
// slice re-read = multi-GB L2 traffic; VGPR=52 proves Wo never sat in regs).
// Blocking rows by 8 cuts Wo re-reads 8x (acc[8] in VGPRs). Stores revert to
// write-back float4: R6's RFO disaster was MISALIGNED (VSK=2000, 8000B base);
// with VSK=2048 every wave store span is full-line -> no RFO expected
// (harness fill: plain stores, 6.9 TB/s, FETCH 36KB). Watch FETCH.
// ---------------------------------------------------------------------------
#define RV 64     // rows per block
#define VSK 2048  // vocab cols per block slice
#define RB 8      // register-blocked rows

__global__ __launch_bounds__(512, 4) void write_logits(
    const float* __restrict__ H, const float* __restrict__ Wo,
    const float* __restrict__ P, float* __restrict__ out)
{
    __shared__ __align__(16) float sH[RV * HID];  // 4 KB
    __shared__ __align__(16) float sLogS[RV];

    const int tid = threadIdx.x;
    const int vtile = blockIdx.x & 15;
    const int row0 = (blockIdx.x >> 4) * RV;

    if (tid < RV * HID / 4)
        *(float4*)(sH + 4 * tid) = *(const float4*)(H + row0 * HID + 4 * tid);
    if (tid < RV) {  // fused logS: 8 partials per row
        float tot = 0.f;
        #pragma unroll
        for (int p = 0; p < 8; ++p) tot += P[(size_t)p * NROW + row0 + tid];
        sLogS[tid] = __logf(tot);
    }
    __syncthreads();

    const int v = vtile * VSK + 4 * tid;
    if (v >= VOCAB) return;  // tile-15 tail; no barriers below

    const float* wp = Wo + v;
    const f32x4* sH4 = (const f32x4*)sH;

    for (int r8 = 0; r8 < RV; r8 += RB) {
        f32x4 acc[RB];
        #pragma unroll
        for (int r = 0; r < RB; ++r) {
            float nls = -sLogS[r8 + r];
            acc[r] = f32x4{nls, nls, nls, nls};
        }
        // k in chunks of 4: h as ds_read_b128 per row (32 b128 / r8-group)
        #pragma unroll
        for (int k4 = 0; k4 < HID / 4; ++k4) {
            f32x4 w0 = *(const f32x4*)(wp + (size_t)(4 * k4 + 0) * VOCAB);
            f32x4 w1 = *(const f32x4*)(wp + (size_t)(4 * k4 + 1) * VOCAB);
            f32x4 w2 = *(const f32x4*)(wp + (size_t)(4 * k4 + 2) * VOCAB);
            f32x4 w3 = *(const f32x4*)(wp + (size_t)(4 * k4 + 3) * VOCAB);
            #pragma unroll
            for (int r = 0; r < RB; ++r) {
                f32x4 h4 = sH4[(r8 + r) * 4 + k4];  // uniform b128 broadcast
                acc[r] += h4.x * w0;
                acc[r] += h4.y * w1;
                acc[r] += h4.z * w2;
                acc[r] += h4.w * w3;
            }
        }
        float* orow = out + (size_t)(row0 + r8) * VOCAB + v;
        #pragma unroll
        for (int r = 0; r < RB; ++r) {
            *(f32x4*)orow = acc[r];  // plain write-back, 128B-aligned span
            orow += VOCAB;
        }
    }
}

extern "C" void kernel_launch(void* const* d_in, const int* in_sizes, int n_in,
                              void* d_out, int out_size, void* d_ws, size_t ws_size,
                              hipStream_t stream) {
    const int*   idx    = (const int*)d_in[0];    // [SEQ, BATCH] int32
    const float* lookup = (const float*)d_in[1];  // [VOCAB, EMB]
    const float* Wx     = (const float*)d_in[2];  // [EMB, HID]
    const float* Wh     = (const float*)d_in[3];  // [HID, HID]
    const float* Wo     = (const float*)d_in[4];  // [HID, VOCAB]
    float* out = (float*)d_out;                   // [SEQ, BATCH, VOCAB]

    // ws layout: H (256 KB) | A = X@Wx (256 KB) | P partials 8x4096 (128 KB)
    float* Hbuf = (float*)d_ws;
    float* A    = Hbuf + NROW * HID;
    float* P    = A + NROW * HID;

    embed_xw<<<128, 512, 0, stream>>>(idx, lookup, Wx, A);
    rnn_recur<<<1, 512, 0, stream>>>(A, Wh, Hbuf);
    sum_exp_partial<<<512, 512, 0, stream>>>(Hbuf, Wo, P);
    write_logits<<<16 * (NROW / RV), 512, 0, stream>>>(Hbuf, Wo, P, out);
}